// Round 15
// baseline (326.552 us; speedup 1.0000x reference)
//
#include <hip/hip_runtime.h>
#include <stdint.h>

#define BATCH 8
#define HIN   28
#define CH    32
#define HO    14
#define NIN   784                 // 28*28
#define NOUT  196                 // 14*14
#define JHALF 392                 // contiguous j-columns per q-half
#define HTILE (98 * CH)           // 3136 words = 12.5KB output half-tile
#define UNROLL 7
#define OUTER  7                  // 49 items/thread x 256 thr = 12544 items

typedef float f32x4 __attribute__((ext_vector_type(4)));

// ---------- Kernel A (tiny): one thread per (b, window q, channel-half) ----
// Computes the 2x2 argmax code once, writes:
//   mu_out  : pooled max (float4 x4)
//   cmq_g[(b*784+j)*2+hf] = (ql*CH)<<16 | mask16   (ql = q - (j>=392)*98)
//   rm_g [(b*196+q)*2+hf] = packed 4x16-bit row masks (bit cl in slice r
//                           iff channel hf*16+cl has argmax code r)
__global__ void vdp_mask_kernel(const float* __restrict__ mu_in,
                                float* __restrict__ mu_out,
                                uint32_t* __restrict__ cmq_g,
                                unsigned long long* __restrict__ rm_g) {
    const int t = blockIdx.x * 256 + threadIdx.x;
    if (t >= BATCH * NOUT * 2) return;
    const int hf = t & 1;
    const int bq = t >> 1;
    const int q  = bq % NOUT;
    const int b  = bq / NOUT;
    const int qy = q / HO, qx = q - qy * HO;

    const float* base =
        mu_in + (((size_t)b * HIN + 2 * qy) * HIN + 2 * qx) * CH + hf * 16;

    uint32_t kqh = 0;
    #pragma unroll
    for (int g = 0; g < 4; ++g) {
        const float4 v0 = *(const float4*)(base + g * 4);
        const float4 v1 = *(const float4*)(base + CH + g * 4);
        const float4 v2 = *(const float4*)(base + HIN * CH + g * 4);
        const float4 v3 = *(const float4*)(base + HIN * CH + CH + g * 4);
        float mu4[4];
        #pragma unroll
        for (int m = 0; m < 4; ++m) {
            const float e0 = (&v0.x)[m], e1 = (&v1.x)[m],
                        e2 = (&v2.x)[m], e3 = (&v3.x)[m];
            float best = e0; uint32_t k = 0;
            if (e1 > best) { best = e1; k = 1; }   // strict >: TF tie rule
            if (e2 > best) { best = e2; k = 2; }
            if (e3 > best) { best = e3; k = 3; }
            mu4[m] = best;
            kqh |= k << (2 * (g * 4 + m));
        }
        *(float4*)(mu_out + (size_t)bq * CH + hf * 16 + g * 4) =
            make_float4(mu4[0], mu4[1], mu4[2], mu4[3]);
    }

    // cmq entries (4 scattered u32) — local-q offset baked in
    const int ql = q - ((qy >= 7) ? 98 : 0);
    const uint32_t qb = (uint32_t)(ql * CH) << 16;
    const int jb = (2 * qy) * HIN + 2 * qx;
    #pragma unroll
    for (int dj = 0; dj < 4; ++dj) {
        uint32_t mm = 0;
        #pragma unroll
        for (int cl = 0; cl < 16; ++cl)
            mm |= (((kqh >> (2 * cl)) & 3u) == (uint32_t)dj) ? (1u << cl) : 0u;
        const int j = jb + (dj >> 1) * HIN + (dj & 1);
        cmq_g[((size_t)b * NIN + j) * 2 + hf] = qb | mm;
    }

    // packed row-mask u64
    unsigned long long rmpack = 0ull;
    #pragma unroll
    for (int r = 0; r < 4; ++r) {
        uint32_t mm = 0;
        #pragma unroll
        for (int cl = 0; cl < 16; ++cl)
            mm |= (((kqh >> (2 * cl)) & 3u) == (uint32_t)r) ? (1u << cl) : 0u;
        rmpack |= (unsigned long long)mm << (16 * r);
    }
    rm_g[(size_t)bq * 2 + hf] = rmpack;
}

// ---------- Kernel B: block = (b, p, qh) — R14 core at 8 blocks/CU ---------
// LDS 16KB x 8 = 128KB < 160KB; 32 waves/CU. VGPR budget 64: the load loop
// keeps only val[7]+selp (~50 live regs); scatter re-reads cmq from LDS
// (ds_read latency hides under the loads' vmcnt wait).
__global__ __launch_bounds__(256, 8) void vdp_pool_half_kernel(
        const float* __restrict__ sigma_in,
        const uint32_t* __restrict__ cmq_g,
        const unsigned long long* __restrict__ rm_g,
        float* __restrict__ sigma_out)
{
    __shared__ __align__(16) float out_tile[HTILE + 64];   // +64 trash words
    __shared__ uint32_t cmq[JHALF * 2];                    // [jl][half16]

    const int bid = blockIdx.x;
    const int qh  = bid & 1;                 // output-row half
    const int bp  = bid >> 1;                // b*NOUT + p
    const int b   = bp / NOUT;
    const int p   = bp - b * NOUT;
    const int tid = threadIdx.x;
    const int py  = p / HO, px = p - py * HO;

    // ---------------- load masks (coalesced, L2-hot) ------------------------
    {
        const uint32_t* src = cmq_g + ((size_t)b * NIN + qh * JHALF) * 2;
        #pragma unroll
        for (int k = 0; k < 4; ++k) {                  // ceil(784/256) = 4
            const int w = tid + k * 256;
            if (w < JHALF * 2) cmq[w] = src[w];
        }
    }
    const uint32_t half16 = ((uint32_t)tid >> 2) & 1u;
    const unsigned long long rmpack = rm_g[(size_t)bp * 2 + half16];
    __syncthreads();

    // ---------------- per-thread constants ----------------------------------
    const uint32_t e     = (uint32_t)tid & 7u;         // 16B chunk in 128B row
    const uint32_t shs   = (e & 3u) * 4u;              // nibble shift
    const uint32_t hw    = e * 4u;                     // word offset in row
    const uint32_t posb  = (uint32_t)tid >> 3;         // 0..31
    const uint32_t ibase = (uint32_t)(2 * py) * HIN + 2u * px;
    const uint32_t trash = HTILE + ((uint32_t)tid & 63u);

    // ---------------- pre-pass: pack select nibbles into registers ----------
    uint32_t selp[OUTER];
    #pragma unroll
    for (int o = 0; o < OUTER; ++o) {
        uint32_t sp = 0;
        #pragma unroll
        for (int u = 0; u < UNROLL; ++u) {
            const uint32_t pos = (uint32_t)(o * UNROLL + u) * 32u + posb;
            const uint32_t r   = pos / JHALF;          // magic-mul
            const uint32_t jl  = pos - r * JHALF;
            const uint32_t sel16 =
                ((uint32_t)(rmpack >> (r * 16u)) & cmq[jl * 2 + half16]) & 0xFFFFu;
            sp |= ((sel16 >> shs) & 0xFu) << (4 * u);
        }
        selp[o] = sp;
    }

    // ---------------- Phase 1: predicated dense stream + LDS scatter --------
    const float* sb = sigma_in + (size_t)b * NIN * NIN * CH
                    + (size_t)qh * JHALF * CH;         // col-half base
    for (int o = 0; o < OUTER; ++o) {
        f32x4 val[UNROLL];
        const uint32_t sp = selp[o];
        #pragma unroll
        for (int u = 0; u < UNROLL; ++u) {
            const uint32_t pos = (uint32_t)(o * UNROLL + u) * 32u + posb;
            const uint32_t r   = pos / JHALF;
            const uint32_t jl  = pos - r * JHALF;
            const uint32_t i   = ibase + (r >> 1) * HIN + (r & 1u);
            val[u] = (f32x4){0.0f, 0.0f, 0.0f, 0.0f};
            if ((sp >> (4 * u)) & 0xFu)                // dead lanes: NO request
                val[u] = __builtin_nontemporal_load(
                    (const f32x4*)(sb + ((size_t)i * NIN + jl) * CH + hw));
        }
        #pragma unroll
        for (int u = 0; u < UNROLL; ++u) {
            const uint32_t pos = (uint32_t)(o * UNROLL + u) * 32u + posb;
            const uint32_t r   = pos / JHALF;
            const uint32_t jl  = pos - r * JHALF;
            const uint32_t tab = cmq[jl * 2 + half16]; // ds_read, hidden
            const uint32_t s4  = (sp >> (4 * u)) & 0xFu;
            const uint32_t bs  = (tab >> 16) + hw;
            out_tile[(s4 & 1u) ? bs + 0u : trash] = val[u][0];
            out_tile[(s4 & 2u) ? bs + 1u : trash] = val[u][1];
            out_tile[(s4 & 4u) ? bs + 2u : trash] = val[u][2];
            out_tile[(s4 & 8u) ? bs + 3u : trash] = val[u][3];
        }
    }
    __syncthreads();

    // ---------------- Phase 2: contiguous NT half-tile write-out ------------
    {
        const f32x4* srcT = (const f32x4*)out_tile;
        f32x4* dstT = (f32x4*)(sigma_out + (size_t)bp * (NOUT * CH)
                               + (size_t)qh * HTILE);
        for (int w = tid; w < HTILE / 4; w += 256)     // 784 f32x4
            __builtin_nontemporal_store(srcT[w], &dstT[w]);
    }
}

extern "C" void kernel_launch(void* const* d_in, const int* in_sizes, int n_in,
                              void* d_out, int out_size, void* d_ws, size_t ws_size,
                              hipStream_t stream) {
    const float* mu_in    = (const float*)d_in[0];
    const float* sigma_in = (const float*)d_in[1];

    float* mu_out    = (float*)d_out;                      // 8*14*14*32 floats
    float* sigma_out = (float*)d_out + BATCH * NOUT * CH;  // 8*196*196*32 floats

    uint32_t* cmq_g = (uint32_t*)d_ws;                     // 8*784*2 u32 = 50KB
    unsigned long long* rm_g =
        (unsigned long long*)((char*)d_ws + BATCH * NIN * 2 * sizeof(uint32_t));
                                                           // 8*196*2 u64 = 25KB

    {
        const int total = BATCH * NOUT * 2;                // 3136
        vdp_mask_kernel<<<(total + 255) / 256, 256, 0, stream>>>(
            mu_in, mu_out, cmq_g, rm_g);
    }
    vdp_pool_half_kernel<<<BATCH * NOUT * 2, 256, 0, stream>>>(
        sigma_in, cmq_g, rm_g, sigma_out);
}

// Round 16
// 112.006 us; speedup vs baseline: 2.9155x; 2.9155x over previous
//
#include <hip/hip_runtime.h>
#include <stdint.h>

#define BATCH 8
#define HIN   28
#define CH    32
#define HO    14
#define NIN   784                 // 28*28
#define NOUT  196                 // 14*14
#define JHALF 392                 // contiguous j-columns per q-half
#define HTILE (98 * CH)           // 3136 words = 12.5KB output half-tile
#define UNROLL 7
#define OUTER  7                  // 49 items/thread x 256 thr = 12544 items

typedef float f32x4 __attribute__((ext_vector_type(4)));

// ---------- Kernel A (tiny): one thread per (b, window q, channel-half) ----
// Computes the 2x2 argmax code once, writes:
//   mu_out  : pooled max (float4 x4)
//   cmq_g[(b*784+j)*2+hf] = (ql*CH)<<16 | mask16   (ql = q - (j>=392)*98)
//   rm_g [(b*196+q)*2+hf] = packed 4x16-bit row masks (bit cl in slice r
//                           iff channel hf*16+cl has argmax code r)
__global__ void vdp_mask_kernel(const float* __restrict__ mu_in,
                                float* __restrict__ mu_out,
                                uint32_t* __restrict__ cmq_g,
                                unsigned long long* __restrict__ rm_g) {
    const int t = blockIdx.x * 256 + threadIdx.x;
    if (t >= BATCH * NOUT * 2) return;
    const int hf = t & 1;
    const int bq = t >> 1;
    const int q  = bq % NOUT;
    const int b  = bq / NOUT;
    const int qy = q / HO, qx = q - qy * HO;

    const float* base =
        mu_in + (((size_t)b * HIN + 2 * qy) * HIN + 2 * qx) * CH + hf * 16;

    uint32_t kqh = 0;
    #pragma unroll
    for (int g = 0; g < 4; ++g) {
        const float4 v0 = *(const float4*)(base + g * 4);
        const float4 v1 = *(const float4*)(base + CH + g * 4);
        const float4 v2 = *(const float4*)(base + HIN * CH + g * 4);
        const float4 v3 = *(const float4*)(base + HIN * CH + CH + g * 4);
        float mu4[4];
        #pragma unroll
        for (int m = 0; m < 4; ++m) {
            const float e0 = (&v0.x)[m], e1 = (&v1.x)[m],
                        e2 = (&v2.x)[m], e3 = (&v3.x)[m];
            float best = e0; uint32_t k = 0;
            if (e1 > best) { best = e1; k = 1; }   // strict >: TF tie rule
            if (e2 > best) { best = e2; k = 2; }
            if (e3 > best) { best = e3; k = 3; }
            mu4[m] = best;
            kqh |= k << (2 * (g * 4 + m));
        }
        *(float4*)(mu_out + (size_t)bq * CH + hf * 16 + g * 4) =
            make_float4(mu4[0], mu4[1], mu4[2], mu4[3]);
    }

    // cmq entries (4 scattered u32) — local-q offset baked in
    const int ql = q - ((qy >= 7) ? 98 : 0);
    const uint32_t qb = (uint32_t)(ql * CH) << 16;
    const int jb = (2 * qy) * HIN + 2 * qx;
    #pragma unroll
    for (int dj = 0; dj < 4; ++dj) {
        uint32_t mm = 0;
        #pragma unroll
        for (int cl = 0; cl < 16; ++cl)
            mm |= (((kqh >> (2 * cl)) & 3u) == (uint32_t)dj) ? (1u << cl) : 0u;
        const int j = jb + (dj >> 1) * HIN + (dj & 1);
        cmq_g[((size_t)b * NIN + j) * 2 + hf] = qb | mm;
    }

    // packed row-mask u64
    unsigned long long rmpack = 0ull;
    #pragma unroll
    for (int r = 0; r < 4; ++r) {
        uint32_t mm = 0;
        #pragma unroll
        for (int cl = 0; cl < 16; ++cl)
            mm |= (((kqh >> (2 * cl)) & 3u) == (uint32_t)r) ? (1u << cl) : 0u;
        rmpack |= (unsigned long long)mm << (16 * r);
    }
    rm_g[(size_t)bq * 2 + hf] = rmpack;
}

// ---------- Kernel B: block = (b, p, qh) — R13 core + register-resolved ----
// true skip: a pre-pass packs each item's 4-bit select nibble into selp[7]
// (registers). Loads keep counter-pure addresses but are exec-predicated on
// the nibble: dead lanes issue NO memory request; a 128B position row whose
// 8 lanes are all dead (P ~ 12.7%) is never fetched.
__global__ __launch_bounds__(256, 6) void vdp_pool_half_kernel(
        const float* __restrict__ sigma_in,
        const uint32_t* __restrict__ cmq_g,
        const unsigned long long* __restrict__ rm_g,
        float* __restrict__ sigma_out)
{
    __shared__ __align__(16) float out_tile[HTILE + 64];   // +64 trash words
    __shared__ uint32_t cmq[JHALF * 2];                    // [jl][half16]

    const int bid = blockIdx.x;
    const int qh  = bid & 1;                 // output-row half
    const int bp  = bid >> 1;                // b*NOUT + p
    const int b   = bp / NOUT;
    const int p   = bp - b * NOUT;
    const int tid = threadIdx.x;
    const int py  = p / HO, px = p - py * HO;

    // ---------------- load masks (coalesced, L2-hot) ------------------------
    {
        const uint32_t* src = cmq_g + ((size_t)b * NIN + qh * JHALF) * 2;
        #pragma unroll
        for (int k = 0; k < 4; ++k) {                  // ceil(784/256) = 4
            const int w = tid + k * 256;
            if (w < JHALF * 2) cmq[w] = src[w];
        }
    }
    const uint32_t half16 = ((uint32_t)tid >> 2) & 1u;
    const unsigned long long rmpack = rm_g[(size_t)bp * 2 + half16];
    __syncthreads();

    // ---------------- per-thread constants ----------------------------------
    const uint32_t e     = (uint32_t)tid & 7u;         // 16B chunk in 128B row
    const uint32_t shs   = (e & 3u) * 4u;              // nibble shift
    const uint32_t hw    = e * 4u;                     // word offset in row
    const uint32_t posb  = (uint32_t)tid >> 3;         // 0..31
    const uint32_t ibase = (uint32_t)(2 * py) * HIN + 2u * px;
    const uint32_t trash = HTILE + ((uint32_t)tid & 63u);

    // ---------------- pre-pass: pack select nibbles into registers ----------
    uint32_t selp[OUTER];
    #pragma unroll
    for (int o = 0; o < OUTER; ++o) {
        uint32_t sp = 0;
        #pragma unroll
        for (int u = 0; u < UNROLL; ++u) {
            const uint32_t pos = (uint32_t)(o * UNROLL + u) * 32u + posb;
            const uint32_t r   = pos / JHALF;          // magic-mul
            const uint32_t jl  = pos - r * JHALF;
            const uint32_t sel16 =
                ((uint32_t)(rmpack >> (r * 16u)) & cmq[jl * 2 + half16]) & 0xFFFFu;
            sp |= ((sel16 >> shs) & 0xFu) << (4 * u);
        }
        selp[o] = sp;
    }

    // ---------------- Phase 1: predicated dense stream + LDS scatter --------
    const float* sb = sigma_in + (size_t)b * NIN * NIN * CH
                    + (size_t)qh * JHALF * CH;         // col-half base
    for (int o = 0; o < OUTER; ++o) {
        f32x4    val[UNROLL];
        uint32_t tab[UNROLL];
        const uint32_t sp = selp[o];
        #pragma unroll
        for (int u = 0; u < UNROLL; ++u) {
            const uint32_t pos = (uint32_t)(o * UNROLL + u) * 32u + posb;
            const uint32_t r   = pos / JHALF;
            const uint32_t jl  = pos - r * JHALF;
            const uint32_t i   = ibase + (r >> 1) * HIN + (r & 1u);
            val[u] = (f32x4){0.0f, 0.0f, 0.0f, 0.0f};
            if ((sp >> (4 * u)) & 0xFu)                // dead lanes: NO request
                val[u] = __builtin_nontemporal_load(
                    (const f32x4*)(sb + ((size_t)i * NIN + jl) * CH + hw));
            tab[u] = cmq[jl * 2 + half16];
        }
        #pragma unroll
        for (int u = 0; u < UNROLL; ++u) {
            const uint32_t s4 = (sp >> (4 * u)) & 0xFu;
            const uint32_t bs = (tab[u] >> 16) + hw;
            out_tile[(s4 & 1u) ? bs + 0u : trash] = val[u][0];
            out_tile[(s4 & 2u) ? bs + 1u : trash] = val[u][1];
            out_tile[(s4 & 4u) ? bs + 2u : trash] = val[u][2];
            out_tile[(s4 & 8u) ? bs + 3u : trash] = val[u][3];
        }
    }
    __syncthreads();

    // ---------------- Phase 2: contiguous NT half-tile write-out ------------
    {
        const f32x4* srcT = (const f32x4*)out_tile;
        f32x4* dstT = (f32x4*)(sigma_out + (size_t)bp * (NOUT * CH)
                               + (size_t)qh * HTILE);
        for (int w = tid; w < HTILE / 4; w += 256)     // 784 f32x4
            __builtin_nontemporal_store(srcT[w], &dstT[w]);
    }
}

extern "C" void kernel_launch(void* const* d_in, const int* in_sizes, int n_in,
                              void* d_out, int out_size, void* d_ws, size_t ws_size,
                              hipStream_t stream) {
    const float* mu_in    = (const float*)d_in[0];
    const float* sigma_in = (const float*)d_in[1];

    float* mu_out    = (float*)d_out;                      // 8*14*14*32 floats
    float* sigma_out = (float*)d_out + BATCH * NOUT * CH;  // 8*196*196*32 floats

    uint32_t* cmq_g = (uint32_t*)d_ws;                     // 8*784*2 u32 = 50KB
    unsigned long long* rm_g =
        (unsigned long long*)((char*)d_ws + BATCH * NIN * 2 * sizeof(uint32_t));
                                                           // 8*196*2 u64 = 25KB

    {
        const int total = BATCH * NOUT * 2;                // 3136
        vdp_mask_kernel<<<(total + 255) / 256, 256, 0, stream>>>(
            mu_in, mu_out, cmq_g, rm_g);
    }
    vdp_pool_half_kernel<<<BATCH * NOUT * 2, 256, 0, stream>>>(
        sigma_in, cmq_g, rm_g, sigma_out);
}